// Round 3
// baseline (694.976 us; speedup 1.0000x reference)
//
#include <hip/hip_runtime.h>

typedef _Float16 half_t;
typedef _Float16 half8  __attribute__((ext_vector_type(8)));
typedef _Float16 half4v __attribute__((ext_vector_type(4)));
typedef float    floatx4 __attribute__((ext_vector_type(4)));

#define NTOK 49
#define DIM  128
#define HEADS 4

// LDS layout (halfs). All offsets 16B-aligned.
#define XH_STRIDE 136                  // x / attn-out staging row stride
#define QK_STRIDE 40                   // q,k row stride
#define VT_STRIDE 72                   // vT row stride
#define P_STRIDE  72
#define XH_HALFS  (NTOK * XH_STRIDE)           // 6664
#define QH_HALFS  (NTOK * QK_STRIDE)           // 1960
#define HEAD_HALFS (2 * QH_HALFS + 32 * VT_STRIDE)  // 6224 (q, k, vT)
#define SMEM_HALFS (XH_HALFS + HEADS * HEAD_HALFS)  // 31560 halfs = 63120 B

#define MFMA16(a, b, c) __builtin_amdgcn_mfma_f32_16x16x32_f16((a), (b), (c), 0, 0, 0)

__device__ inline half8 cvt8(const float* __restrict__ p) {
    float4 w0 = *(const float4*)p;
    float4 w1 = *(const float4*)(p + 4);
    half8 r;
    r[0] = (half_t)w0.x; r[1] = (half_t)w0.y; r[2] = (half_t)w0.z; r[3] = (half_t)w0.w;
    r[4] = (half_t)w1.x; r[5] = (half_t)w1.y; r[6] = (half_t)w1.z; r[7] = (half_t)w1.w;
    return r;
}

__global__ __launch_bounds__(256, 2)
void winattn(const float* __restrict__ x, const float* __restrict__ qkv_w,
             const float* __restrict__ qkv_b, const float* __restrict__ proj_w,
             const float* __restrict__ proj_b, const float* __restrict__ bias_table,
             float* __restrict__ out, int nwin)
{
    __shared__ half_t smem[SMEM_HALFS];
    const int tid  = threadIdx.x;
    const int wid  = tid >> 6;        // wave id == head id
    const int lane = tid & 63;
    const int quad = lane >> 4;
    const int cl   = lane & 15;
    const int win  = blockIdx.x;
    if (win >= nwin) return;

    const floatx4 Z4 = {0.f, 0.f, 0.f, 0.f};

    half_t* const qh = smem + XH_HALFS + wid * HEAD_HALFS;   // [49][40]
    half_t* const kh = qh + QH_HALFS;                        // [49][40] (later aliased by P [16][72])
    half_t* const vT = qh + 2 * QH_HALFS;                    // [32][72]

    // Row-clamp for all fragment reads: rows 49..63 of every token-indexed LDS
    // buffer are never written; clamping to row 48 makes every LDS read
    // touch written-only data => kernel is bit-deterministic run-to-run.
    // (Duplicated row-48 data lands only in masked rows/cols.)
#define CLAMP48(r_) ((r_) < 48 ? (r_) : 48)

    // ---------------- phase 1: stage x window as fp16 ----------------
    const float* xp = x + (size_t)win * (NTOK * DIM);
    for (int i4 = tid; i4 < NTOK * DIM / 4; i4 += 256) {
        float4 v = ((const float4*)xp)[i4];
        int f = i4 << 2, tok = f >> 7, ch = f & 127;
        half4v h;
        h[0] = (half_t)v.x; h[1] = (half_t)v.y; h[2] = (half_t)v.z; h[3] = (half_t)v.w;
        *(half4v*)(smem + tok * XH_STRIDE + ch) = h;
    }
    __syncthreads();

    // ---------------- phase 2: QKV GEMM (per wave: its head's q,k,v cols) ----------------
    half8 a[4][4];
#pragma unroll
    for (int mt = 0; mt < 4; ++mt) {
        const int ar = CLAMP48(mt * 16 + cl);
#pragma unroll
        for (int ks = 0; ks < 4; ++ks)
            a[mt][ks] = *(const half8*)(smem + ar * XH_STRIDE + ks * 32 + quad * 8);
    }

    const float scale = 0.17677669529663687f;  // 32^-0.5
#pragma unroll
    for (int cg = 0; cg < 6; ++cg) {
        const int typ = cg >> 1;  // 0=q 1=k 2=v
        const int nb  = typ * 128 + wid * 32 + (cg & 1) * 16;
        const int n   = nb + cl;
        floatx4 acc[4];
#pragma unroll
        for (int mt = 0; mt < 4; ++mt) acc[mt] = Z4;
#pragma unroll
        for (int ks = 0; ks < 4; ++ks) {
            half8 b = cvt8(qkv_w + n * DIM + ks * 32 + quad * 8);
#pragma unroll
            for (int mt = 0; mt < 4; ++mt) acc[mt] = MFMA16(a[mt][ks], b, acc[mt]);
        }
        const float bias = qkv_b[n];
        const int lc = (cg & 1) * 16 + cl;
        if (typ == 0) {
#pragma unroll
            for (int mt = 0; mt < 4; ++mt)
#pragma unroll
                for (int r = 0; r < 4; ++r) {
                    int tok = mt * 16 + quad * 4 + r;
                    if (tok < NTOK) qh[tok * QK_STRIDE + lc] = (half_t)((acc[mt][r] + bias) * scale);
                }
        } else if (typ == 1) {
#pragma unroll
            for (int mt = 0; mt < 4; ++mt)
#pragma unroll
                for (int r = 0; r < 4; ++r) {
                    int tok = mt * 16 + quad * 4 + r;
                    if (tok < NTOK) kh[tok * QK_STRIDE + lc] = (half_t)(acc[mt][r] + bias);
                }
        } else {
#pragma unroll
            for (int mt = 0; mt < 4; ++mt) {
                int t0 = mt * 16 + quad * 4;
                half4v hv;
#pragma unroll
                for (int r = 0; r < 4; ++r) hv[r] = (half_t)(acc[mt][r] + bias);
                *(half4v*)(vT + lc * VT_STRIDE + t0) = hv;  // transposed store: 4 consecutive tokens
            }
        }
    }
    // Re-zero vT pad tokens 49..63 so P(=0) x v stays exactly 0.
    for (int i = lane; i < 512; i += 64) {
        int cc = i >> 4, tt = i & 15;
        if (tt) vT[cc * VT_STRIDE + 48 + tt] = (half_t)0.f;
    }
    __syncthreads();  // all waves done reading xh; it becomes the attn-out staging buffer

    // ---------------- phase 3: attention for head = wid ----------------
    int K1[4];
#pragma unroll
    for (int nt = 0; nt < 4; ++nt) {
        int colc = CLAMP48(nt * 16 + cl);
        int kr   = (colc * 37) >> 8;        // colc / 7 (valid for 0..48)
        int kc   = colc - kr * 7;
        K1[nt]   = kr * 13 + kc;
    }
    const bool cm3 = (cl == 0);  // N-tile 3: only col 48 is a valid key

    half8 kf[4], vf[2][2];
#pragma unroll
    for (int nt = 0; nt < 4; ++nt)
        kf[nt] = *(const half8*)(kh + CLAMP48(nt * 16 + cl) * QK_STRIDE + quad * 8);
#pragma unroll
    for (int ks = 0; ks < 2; ++ks)
#pragma unroll
        for (int nt = 0; nt < 2; ++nt)
            vf[ks][nt] = *(const half8*)(vT + (nt * 16 + cl) * VT_STRIDE + ks * 32 + quad * 8);

    half_t* const Pb = kh;  // k fragments consumed above; alias its LDS for P
    const float* bt = bias_table;

#pragma unroll
    for (int mt = 0; mt < 4; ++mt) {
        half8 qf = *(const half8*)(qh + CLAMP48(mt * 16 + cl) * QK_STRIDE + quad * 8);
        floatx4 s[4];
#pragma unroll
        for (int nt = 0; nt < 4; ++nt)
            s[nt] = MFMA16(qf, kf[nt], Z4);

        float sv[4][4];
#pragma unroll
        for (int r = 0; r < 4; ++r) {
            int tc  = CLAMP48(mt * 16 + quad * 4 + r);
            int qr  = (tc * 37) >> 8;
            int qc  = tc - qr * 7;
            int Q1  = qr * 13 + qc + 84;
#pragma unroll
            for (int nt = 0; nt < 4; ++nt)
                sv[nt][r] = s[nt][r] + bt[(Q1 - K1[nt]) * HEADS + wid];
        }
#pragma unroll
        for (int r = 0; r < 4; ++r) sv[3][r] = cm3 ? sv[3][r] : -1e30f;

        float mx[4], sum[4], ex[4][4];
#pragma unroll
        for (int r = 0; r < 4; ++r)
            mx[r] = fmaxf(fmaxf(sv[0][r], sv[1][r]), fmaxf(sv[2][r], sv[3][r]));
#pragma unroll
        for (int off = 1; off < 16; off <<= 1)
#pragma unroll
            for (int r = 0; r < 4; ++r) mx[r] = fmaxf(mx[r], __shfl_xor(mx[r], off, 16));
#pragma unroll
        for (int r = 0; r < 4; ++r) {
            sum[r] = 0.f;
#pragma unroll
            for (int nt = 0; nt < 4; ++nt) {
                float e = __expf(sv[nt][r] - mx[r]);
                ex[nt][r] = e;
                sum[r] += e;
            }
        }
#pragma unroll
        for (int off = 1; off < 16; off <<= 1)
#pragma unroll
            for (int r = 0; r < 4; ++r) sum[r] += __shfl_xor(sum[r], off, 16);

#pragma unroll
        for (int r = 0; r < 4; ++r) {
            float rinv = 1.0f / sum[r];
#pragma unroll
            for (int nt = 0; nt < 4; ++nt)
                Pb[(quad * 4 + r) * P_STRIDE + nt * 16 + cl] = (half_t)(ex[nt][r] * rinv);
        }

        half8 pf0 = *(const half8*)(Pb + cl * P_STRIDE + quad * 8);
        half8 pf1 = *(const half8*)(Pb + cl * P_STRIDE + 32 + quad * 8);
        floatx4 o0 = Z4, o1 = Z4;
        o0 = MFMA16(pf0, vf[0][0], o0); o0 = MFMA16(pf1, vf[1][0], o0);
        o1 = MFMA16(pf0, vf[0][1], o1); o1 = MFMA16(pf1, vf[1][1], o1);

#pragma unroll
        for (int r = 0; r < 4; ++r) {
            int tok = mt * 16 + quad * 4 + r;
            if (tok < NTOK) {
                smem[tok * XH_STRIDE + wid * 32 + cl]      = (half_t)o0[r];
                smem[tok * XH_STRIDE + wid * 32 + 16 + cl] = (half_t)o1[r];
            }
        }
    }
    __syncthreads();  // attn-out staging complete for all heads

    // ---------------- phase 5: proj GEMM ----------------
    half8 pw[2][4];
    const int nbase = wid * 32;
#pragma unroll
    for (int nt = 0; nt < 2; ++nt)
#pragma unroll
        for (int ks = 0; ks < 4; ++ks)
            pw[nt][ks] = cvt8(proj_w + (nbase + nt * 16 + cl) * DIM + ks * 32 + quad * 8);
    float pb0 = proj_b[nbase + cl];
    float pb1 = proj_b[nbase + 16 + cl];

    float* ow = out + (size_t)win * (NTOK * DIM);
#pragma unroll
    for (int mt = 0; mt < 4; ++mt) {
        floatx4 a0 = Z4, a1 = Z4;
        const int ar = CLAMP48(mt * 16 + cl);
#pragma unroll
        for (int ks = 0; ks < 4; ++ks) {
            half8 af = *(const half8*)(smem + ar * XH_STRIDE + ks * 32 + quad * 8);
            a0 = MFMA16(af, pw[0][ks], a0);
            a1 = MFMA16(af, pw[1][ks], a1);
        }
#pragma unroll
        for (int r = 0; r < 4; ++r) {
            int tok = mt * 16 + quad * 4 + r;
            if (tok < NTOK) {
                ow[tok * DIM + nbase + cl]      = a0[r] + pb0;
                ow[tok * DIM + nbase + 16 + cl] = a1[r] + pb1;
            }
        }
    }
}

extern "C" void kernel_launch(void* const* d_in, const int* in_sizes, int n_in,
                              void* d_out, int out_size, void* d_ws, size_t ws_size,
                              hipStream_t stream) {
    const float* x          = (const float*)d_in[0];
    const float* qkv_w      = (const float*)d_in[1];
    const float* qkv_b      = (const float*)d_in[2];
    const float* proj_w     = (const float*)d_in[3];
    const float* proj_b     = (const float*)d_in[4];
    const float* bias_table = (const float*)d_in[5];
    // d_in[6] (rel_index) is recomputed analytically in-kernel.
    const int nwin = in_sizes[0] / (NTOK * DIM);
    winattn<<<nwin, 256, 0, stream>>>(x, qkv_w, qkv_b, proj_w, proj_b,
                                      bias_table, (float*)d_out, nwin);
}